// Round 2
// baseline (67.296 us; speedup 1.0000x reference)
//
#include <hip/hip_runtime.h>

// loss = || F^T F - S^T S ||_F^2 / 2^38
// F = input.reshape(64, 8192).T, S = target.reshape(64, 8192).T
// (exact rewrite of sum((FF^T+c)^d + (SS^T+c)^d - 2(FS^T+c)^d) for c=0, d=2)

#define CH    64
#define KTOT  8192
#define G1    512            // gram blocks
#define KPB   (KTOT / G1)    // 16 k per block
#define NGRP  2              // thread groups per block (512 threads)
#define KPG   (KPB / NGRP)   // 8 k per group

// 1 / (8192 * 8192 * 64 * 64) = 2^-38
#define NORMF 3.637978807091713e-12f

__global__ __launch_bounds__(512, 4) void gram_partial(
    const float* __restrict__ in, const float* __restrict__ tg,
    float* __restrict__ ws)
{
    // Transposed tiles [k][ch]: fragment reads contiguous in ch.
    __shared__ __attribute__((aligned(16))) float ts_in[KPB][CH];   // 4 KiB
    __shared__ __attribute__((aligned(16))) float ts_tg[KPB][CH];   // 4 KiB
    __shared__ __attribute__((aligned(16))) float red[4096];        // 16 KiB

    const int t  = threadIdx.x;            // 0..511
    const int k0 = blockIdx.x * KPB;

    // --- stage: thread t loads one float2 per matrix ---
    {
        const int lch = t >> 3;            // 0..63
        const int lko = (t & 7) << 1;      // 0,2,..,14
        const float2 vi = *(const float2*)(in + lch * KTOT + k0 + lko);
        const float2 vt = *(const float2*)(tg + lch * KTOT + k0 + lko);
        ts_in[lko + 0][lch] = vi.x; ts_in[lko + 1][lch] = vi.y;
        ts_tg[lko + 0][lch] = vt.x; ts_tg[lko + 1][lch] = vt.y;
    }
    __syncthreads();

    // --- compute: group g handles kk in [g*KPG, (g+1)*KPG) ---
    const int g   = t >> 8;                // 0..1
    const int tid = t & 255;               // 0..255
    const int ty  = tid >> 4;              // 0..15
    const int tx  = tid & 15;              // 0..15
    const int a0  = ty << 2;
    const int b0  = tx << 2;

    float acc[4][4];
#pragma unroll
    for (int i = 0; i < 4; ++i)
#pragma unroll
        for (int j = 0; j < 4; ++j) acc[i][j] = 0.f;

#pragma unroll
    for (int kk = g * KPG; kk < g * KPG + KPG; ++kk) {
        const float4 av = *(const float4*)&ts_in[kk][a0];
        const float4 bv = *(const float4*)&ts_in[kk][b0];
        const float4 cv = *(const float4*)&ts_tg[kk][a0];
        const float4 dv = *(const float4*)&ts_tg[kk][b0];
        const float aa[4] = {av.x, av.y, av.z, av.w};
        const float bb[4] = {bv.x, bv.y, bv.z, bv.w};
        const float cc[4] = {cv.x, cv.y, cv.z, cv.w};
        const float dd[4] = {dv.x, dv.y, dv.z, dv.w};
#pragma unroll
        for (int i = 0; i < 4; ++i)
#pragma unroll
            for (int j = 0; j < 4; ++j) {
                acc[i][j] = fmaf(aa[i], bb[j], acc[i][j]);
                acc[i][j] = fmaf(-cc[i], dd[j], acc[i][j]);
            }
    }

    // --- block reduce (group 1 -> LDS, group 0 adds) and store ---
    if (g == 1) {
#pragma unroll
        for (int i = 0; i < 4; ++i) {
            float4 v;
            v.x = acc[i][0]; v.y = acc[i][1]; v.z = acc[i][2]; v.w = acc[i][3];
            *(float4*)&red[tid * 16 + i * 4] = v;
        }
    }
    __syncthreads();
    if (g == 0) {
        float* p = ws + blockIdx.x * 4096;
#pragma unroll
        for (int i = 0; i < 4; ++i) {
            const float4 r = *(const float4*)&red[tid * 16 + i * 4];
            float4 v;
            v.x = acc[i][0] + r.x; v.y = acc[i][1] + r.y;
            v.z = acc[i][2] + r.z; v.w = acc[i][3] + r.w;
            *(float4*)(p + (a0 + i) * 64 + b0) = v;
        }
    }
}

__global__ __launch_bounds__(256) void reduce_square(
    const float* __restrict__ ws, float* __restrict__ out)
{
    // 128 blocks x 32 entries; 8 slices of 64 partials per entry
    __shared__ float red2[8][32];
    const int t  = threadIdx.x;
    const int el = t & 31;                     // entry within block
    const int sl = t >> 5;                     // 0..7
    const int e  = (blockIdx.x << 5) + el;     // gram entry 0..4095

    float s = 0.f;
    const int p0 = sl * (G1 / 8);
#pragma unroll 16
    for (int p = p0; p < p0 + (G1 / 8); ++p)
        s += ws[p * 4096 + e];
    red2[sl][el] = s;
    __syncthreads();

    if (t < 32) {                              // within wave 0
        float tot = 0.f;
#pragma unroll
        for (int i = 0; i < 8; ++i) tot += red2[i][t];
        float sq = tot * tot;
#pragma unroll
        for (int off = 16; off > 0; off >>= 1)
            sq += __shfl_down(sq, off);
        if (t == 0) atomicAdd(out, sq * NORMF);
    }
}

extern "C" void kernel_launch(void* const* d_in, const int* in_sizes, int n_in,
                              void* d_out, int out_size, void* d_ws, size_t ws_size,
                              hipStream_t stream)
{
    const float* in = (const float*)d_in[0];
    const float* tg = (const float*)d_in[1];
    float* out = (float*)d_out;
    float* ws  = (float*)d_ws;   // uses G1*4096*4 = 8 MiB

    hipMemsetAsync(out, 0, sizeof(float), stream);
    gram_partial<<<G1, 512, 0, stream>>>(in, tg, ws);
    reduce_square<<<128, 256, 0, stream>>>(ws, out);
}

// Round 3
// 63.561 us; speedup vs baseline: 1.0588x; 1.0588x over previous
//
#include <hip/hip_runtime.h>

// loss = || F^T F - S^T S ||_F^2 / 2^38
// F = input.reshape(64, 8192).T, S = target.reshape(64, 8192).T
// Exact rewrite of sum((FF^T+c)^d + (SS^T+c)^d - 2(FS^T+c)^d) for c=0, d=2:
//   sum_ij (f_i.f_j)^2 = ||F^T F||_F^2  etc., cross term = <F^T F, S^T S>.

#define CH    64
#define KTOT  8192
#define G1    256            // gram blocks
#define KPB   (KTOT / G1)    // 32 k per block
#define KPG   (KPB / 2)      // 16 k per 256-thread group

// 1 / (8192 * 8192 * 64 * 64) = 2^-38
#define NORMF 3.637978807091713e-12f

__global__ __launch_bounds__(512, 4) void gram_partial(
    const float* __restrict__ in, const float* __restrict__ tg,
    float* __restrict__ ws, float* __restrict__ out)
{
    // Transposed tiles [k][ch]: fragment reads contiguous in ch.
    __shared__ __attribute__((aligned(16))) float ts_in[KPB][CH];   // 8 KiB
    __shared__ __attribute__((aligned(16))) float ts_tg[KPB][CH];   // 8 KiB
    __shared__ __attribute__((aligned(16))) float red[4096];        // 16 KiB

    const int t  = threadIdx.x;            // 0..511
    const int k0 = blockIdx.x * KPB;

    // zero the output accumulator (ordered before reduce_square's atomics
    // by the kernel boundary)
    if (blockIdx.x == 0 && t == 0) out[0] = 0.f;

    // --- stage: thread t loads one float4 per matrix ---
    {
        const int lch = t >> 3;            // 0..63
        const int lko = (t & 7) << 2;      // 0,4,..,28
        const float4 vi = *(const float4*)(in + lch * KTOT + k0 + lko);
        const float4 vt = *(const float4*)(tg + lch * KTOT + k0 + lko);
        ts_in[lko + 0][lch] = vi.x; ts_in[lko + 1][lch] = vi.y;
        ts_in[lko + 2][lch] = vi.z; ts_in[lko + 3][lch] = vi.w;
        ts_tg[lko + 0][lch] = vt.x; ts_tg[lko + 1][lch] = vt.y;
        ts_tg[lko + 2][lch] = vt.z; ts_tg[lko + 3][lch] = vt.w;
    }
    __syncthreads();

    // --- compute: group g handles kk in [g*KPG, (g+1)*KPG) ---
    const int g   = t >> 8;                // 0..1
    const int tid = t & 255;               // 0..255
    const int ty  = tid >> 4;              // 0..15
    const int tx  = tid & 15;              // 0..15
    const int a0  = ty << 2;
    const int b0  = tx << 2;

    float acc[4][4];
#pragma unroll
    for (int i = 0; i < 4; ++i)
#pragma unroll
        for (int j = 0; j < 4; ++j) acc[i][j] = 0.f;

#pragma unroll
    for (int kk = g * KPG; kk < g * KPG + KPG; ++kk) {
        const float4 av = *(const float4*)&ts_in[kk][a0];
        const float4 bv = *(const float4*)&ts_in[kk][b0];
        const float4 cv = *(const float4*)&ts_tg[kk][a0];
        const float4 dv = *(const float4*)&ts_tg[kk][b0];
        const float aa[4] = {av.x, av.y, av.z, av.w};
        const float bb[4] = {bv.x, bv.y, bv.z, bv.w};
        const float cc[4] = {cv.x, cv.y, cv.z, cv.w};
        const float dd[4] = {dv.x, dv.y, dv.z, dv.w};
#pragma unroll
        for (int i = 0; i < 4; ++i)
#pragma unroll
            for (int j = 0; j < 4; ++j) {
                acc[i][j] = fmaf(aa[i], bb[j], acc[i][j]);
                acc[i][j] = fmaf(-cc[i], dd[j], acc[i][j]);
            }
    }

    // --- block reduce (group 1 -> LDS, group 0 adds) and store ---
    if (g == 1) {
#pragma unroll
        for (int i = 0; i < 4; ++i) {
            float4 v;
            v.x = acc[i][0]; v.y = acc[i][1]; v.z = acc[i][2]; v.w = acc[i][3];
            *(float4*)&red[tid * 16 + i * 4] = v;
        }
    }
    __syncthreads();
    if (g == 0) {
        float* p = ws + blockIdx.x * 4096;
#pragma unroll
        for (int i = 0; i < 4; ++i) {
            const float4 r = *(const float4*)&red[tid * 16 + i * 4];
            float4 v;
            v.x = acc[i][0] + r.x; v.y = acc[i][1] + r.y;
            v.z = acc[i][2] + r.z; v.w = acc[i][3] + r.w;
            *(float4*)(p + (a0 + i) * 64 + b0) = v;
        }
    }
}

__global__ __launch_bounds__(256) void reduce_square(
    const float* __restrict__ ws, float* __restrict__ out)
{
    // 64 blocks x 64 entries; 4 slices of 64 partials per entry
    __shared__ float red2[4][64];
    const int t  = threadIdx.x;
    const int el = t & 63;                     // entry within block
    const int sl = t >> 6;                     // 0..3
    const int e  = (blockIdx.x << 6) + el;     // gram entry 0..4095

    float s = 0.f;
    const int p0 = sl * (G1 / 4);
#pragma unroll 16
    for (int p = p0; p < p0 + (G1 / 4); ++p)
        s += ws[p * 4096 + e];
    red2[sl][el] = s;
    __syncthreads();

    if (t < 64) {                              // wave 0
        float tot = red2[0][t] + red2[1][t] + red2[2][t] + red2[3][t];
        float sq  = tot * tot;
#pragma unroll
        for (int off = 32; off > 0; off >>= 1)
            sq += __shfl_down(sq, off);
        if (t == 0) atomicAdd(out, sq * NORMF);
    }
}

extern "C" void kernel_launch(void* const* d_in, const int* in_sizes, int n_in,
                              void* d_out, int out_size, void* d_ws, size_t ws_size,
                              hipStream_t stream)
{
    const float* in = (const float*)d_in[0];
    const float* tg = (const float*)d_in[1];
    float* out = (float*)d_out;
    float* ws  = (float*)d_ws;   // uses G1*4096*4 = 4 MiB

    gram_partial<<<G1, 512, 0, stream>>>(in, tg, ws, out);
    reduce_square<<<64, 256, 0, stream>>>(ws, out);
}